// Round 8
// baseline (137.899 us; speedup 1.0000x reference)
//
#include <hip/hip_runtime.h>

#define N_ 8
#define C_ 48
#define H_ 48
#define W_ 64
#define HO 384
#define WO 512
#define HW 3072

typedef float f32x4 __attribute__((ext_vector_type(4)));

__device__ __forceinline__ unsigned short f2bf(float x) {
    unsigned int u = __float_as_uint(x);
    u += 0x7FFFu + ((u >> 16) & 1u);          // round-to-nearest-even
    return (unsigned short)(u >> 16);
}

// K1: softmax over 9 taps -> bf16 weights ws[n][h][k][pl][wi][q]
// flat ws index: ((nh*9 + k)*8 + pl)*512 + wi*8 + q
__global__ __launch_bounds__(256) void k1_softmax(
    const float* __restrict__ mask, unsigned short* __restrict__ ws)
{
    const int f   = blockIdx.x * 256 + threadIdx.x;  // ((n*H+h)*64+sp)*16 + wiq
    const int wiq = f & 15;
    const int sp  = (f >> 4) & 63;
    const int nh  = f >> 10;
    const int h   = nh % H_;
    const int n   = nh / H_;
    const int pl  = sp >> 3, q = sp & 7;

    const float* mp = mask + ((size_t)(n * 576 + sp) * H_ + h) * W_ + wiq * 4;
    f32x4 v[9];
    #pragma unroll
    for (int k = 0; k < 9; ++k)
        v[k] = *(const f32x4*)(mp + (size_t)k * 64 * HW);
    f32x4 mx = v[0];
    #pragma unroll
    for (int k = 1; k < 9; ++k) {
        mx.x = fmaxf(mx.x, v[k].x); mx.y = fmaxf(mx.y, v[k].y);
        mx.z = fmaxf(mx.z, v[k].z); mx.w = fmaxf(mx.w, v[k].w);
    }
    f32x4 s = (f32x4){0.f, 0.f, 0.f, 0.f};
    #pragma unroll
    for (int k = 0; k < 9; ++k) {
        v[k].x = __expf(v[k].x - mx.x); v[k].y = __expf(v[k].y - mx.y);
        v[k].z = __expf(v[k].z - mx.z); v[k].w = __expf(v[k].w - mx.w);
        s += v[k];
    }
    f32x4 inv;
    inv.x = 1.f / s.x; inv.y = 1.f / s.y; inv.z = 1.f / s.z; inv.w = 1.f / s.w;
    #pragma unroll
    for (int k = 0; k < 9; ++k) {
        f32x4 wv = v[k] * inv;
        unsigned short* wp = ws + ((size_t)(nh * 9 + k) * 8 + pl) * 512 + q;
        wp[(wiq * 4 + 0) * 8] = f2bf(wv.x);
        wp[(wiq * 4 + 1) * 8] = f2bf(wv.y);
        wp[(wiq * 4 + 2) * 8] = f2bf(wv.z);
        wp[(wiq * 4 + 3) * 8] = f2bf(wv.w);
    }
}

// K2: block (n, c-quad, h) writes 4 channels x 16KB fully-contiguous rows.
// XCD-swizzled bid so each XCD sweeps a contiguous region of out.
__global__ __launch_bounds__(256) void k2_combine(
    const float* __restrict__ inp, const unsigned short* __restrict__ ws,
    float* __restrict__ out)
{
    const int raw = blockIdx.x;
    const int L  = (raw & 7) * 576 + (raw >> 3);   // 4608 blocks, %8==0 -> bijective
    const int n  = L / 576;
    const int rm = L % 576;
    const int cq = rm / 48;
    const int h  = rm % 48;

    const int t   = threadIdx.x;
    const int ch2 = t >> 7;            // c-pair within quad
    const int tq  = t & 127;
    const int q4  = tq & 1;            // q quad
    const int wi  = tq >> 1;           // 0..63
    const int c0  = cq * 4 + ch2 * 2;

    const bool r0 = h >= 1, r2 = h <= H_ - 2, d0 = wi >= 1, d2 = wi <= W_ - 2;
    const bool ok[3][3] = {
        { r0 && d0, r0, r0 && d2 },
        { d0,       true, d2     },
        { r2 && d0, r2, r2 && d2 },
    };

    // taps: 9 scalars per channel, shared across all 64 (p,q) outputs
    float tp[2][9];
    #pragma unroll
    for (int c = 0; c < 2; ++c)
        #pragma unroll
        for (int di = 0; di < 3; ++di)
            #pragma unroll
            for (int dj = 0; dj < 3; ++dj) {
                const float* p = inp
                    + ((size_t)((n * C_ + c0 + c) * H_ + h - 1 + di)) * W_ + wi - 1 + dj;
                tp[c][di * 3 + dj] = ok[di][dj] ? *p : 0.f;
            }

    const unsigned short* wb = ws + (size_t)(n * H_ + h) * 9 * 4096 + wi * 8 + q4 * 4;
    float* ob = out + ((size_t)(n * C_ + c0) * HO + h * 8) * WO + wi * 8 + q4 * 4;

    #pragma unroll 2
    for (int pl = 0; pl < 8; ++pl) {
        f32x4 w[9];
        #pragma unroll
        for (int k = 0; k < 9; ++k) {
            uint2 rv = *(const uint2*)(wb + (size_t)(k * 8 + pl) * 512);
            w[k].x = __uint_as_float(rv.x << 16);
            w[k].y = __uint_as_float(rv.x & 0xFFFF0000u);
            w[k].z = __uint_as_float(rv.y << 16);
            w[k].w = __uint_as_float(rv.y & 0xFFFF0000u);
        }
        #pragma unroll
        for (int c = 0; c < 2; ++c) {
            f32x4 acc = w[0] * tp[c][0];
            #pragma unroll
            for (int k = 1; k < 9; ++k) acc += w[k] * tp[c][k];
            *(f32x4*)(ob + ((size_t)c * HO + pl) * WO) = acc;
        }
    }
}

extern "C" void kernel_launch(void* const* d_in, const int* in_sizes, int n_in,
                              void* d_out, int out_size, void* d_ws, size_t ws_size,
                              hipStream_t stream) {
    const float* inp  = (const float*)d_in[0];
    const float* mask = (const float*)d_in[1];
    float* out = (float*)d_out;
    unsigned short* ws = (unsigned short*)d_ws;   // 28,311,552 B used

    k1_softmax<<<(N_ * H_ * 64 * 16) / 256, 256, 0, stream>>>(mask, ws);
    k2_combine<<<N_ * 12 * H_, 256, 0, stream>>>(inp, ws, out);
}

// Round 9
// 99.701 us; speedup vs baseline: 1.3831x; 1.3831x over previous
//
#include <hip/hip_runtime.h>

#define N_ 8
#define C_ 48
#define H_ 48
#define W_ 64
#define HO 384
#define WO 512
#define HW (H_*W_)   // 3072

typedef float f32x4 __attribute__((ext_vector_type(4)));

// out[n][c][h*8+p][w*8+q] = sum_k softmax_k(mask[n][k*64+p*8+q][h][w]) * inp_pad[n][c][h+di-1][w+dj-1]
// Zero-LDS design (R6) + XCD chunk-swizzle: XCD x owns batch n=x, so each
// XCD sweeps a contiguous 37.7MB output region (dense write streams) and a
// private 7MB mask slice (L2-local reads). Everything else identical to R6.
__global__ __launch_bounds__(256, 3) void raft_up_kernel(
    const float* __restrict__ inp, const float* __restrict__ mask,
    float* __restrict__ out)
{
    const int t   = threadIdx.x;
    const int raw = blockIdx.x;
    // 1536 blocks = 8 XCDs * 192; round-robin dispatch -> XCD (raw&7) gets
    // contiguous bid range [x*192, (x+1)*192) = exactly batch n=x.
    const int bid = (raw & 7) * 192 + (raw >> 3);
    const int pg  = bid & 3;
    const int h   = (bid >> 2) % H_;
    const int n   = bid / (4 * H_);

    const int tq    = t & 127;
    const int chalf = t >> 7;              // 0: c 0..23, 1: c 24..47
    const int q4    = tq & 1;              // q quad (q = q4*4 + j)
    const int wi    = tq >> 1;             // 0..63 (w coordinate)

    // ---- softmax over 9 taps for my 8 planes (pl x 4 q's); f32x4 lanes = j (q)
    // global mask channel = k*64 + (pg*2+pl)*8 + q4*4 + j
    f32x4 w[2][9];
    {
        const float* mb = mask + ((size_t)n * 576 + pg * 16 + q4 * 4) * HW
                               + h * W_ + wi;
        #pragma unroll
        for (int pl = 0; pl < 2; ++pl)
            #pragma unroll
            for (int k = 0; k < 9; ++k)
                #pragma unroll
                for (int j = 0; j < 4; ++j)
                    w[pl][k][j] = mb[(size_t)(k * 64 + pl * 8 + j) * HW];

        #pragma unroll
        for (int pl = 0; pl < 2; ++pl) {
            f32x4 mx = w[pl][0];
            #pragma unroll
            for (int k = 1; k < 9; ++k) {
                mx.x = fmaxf(mx.x, w[pl][k].x); mx.y = fmaxf(mx.y, w[pl][k].y);
                mx.z = fmaxf(mx.z, w[pl][k].z); mx.w = fmaxf(mx.w, w[pl][k].w);
            }
            f32x4 s = (f32x4){0.f, 0.f, 0.f, 0.f};
            #pragma unroll
            for (int k = 0; k < 9; ++k) {
                f32x4 e;
                e.x = __expf(w[pl][k].x - mx.x);
                e.y = __expf(w[pl][k].y - mx.y);
                e.z = __expf(w[pl][k].z - mx.z);
                e.w = __expf(w[pl][k].w - mx.w);
                w[pl][k] = e;
                s += e;
            }
            f32x4 inv;
            inv.x = 1.f / s.x; inv.y = 1.f / s.y;
            inv.z = 1.f / s.z; inv.w = 1.f / s.w;
            #pragma unroll
            for (int k = 0; k < 9; ++k) w[pl][k] *= inv;
        }
    }

    // ---- tap validity (zero padding)
    const bool rok0 = (h >= 1), rok2 = (h <= H_ - 2);
    const bool cok0 = (wi >= 1), cok2 = (wi <= W_ - 2);
    const bool ok[3][3] = {
        { rok0 && cok0, rok0, rok0 && cok2 },
        { cok0,         true, cok2         },
        { rok2 && cok0, rok2, rok2 && cok2 },
    };

    const float* ib = inp + (size_t)(n * C_ + chalf * 24) * HW + (wi - 1);
    float* outb = out + ((size_t)(n * C_ + chalf * 24) * HO + h * 8 + pg * 2) * WO
                      + wi * 8 + q4 * 4;

    for (int cblk = 0; cblk < 6; ++cblk) {
        // taps for 4 channels, read straight from L2-resident inp
        float tp[4][9];
        #pragma unroll
        for (int di = 0; di < 3; ++di)
            #pragma unroll
            for (int dj = 0; dj < 3; ++dj) {
                const bool o = ok[di][dj];
                #pragma unroll
                for (int cc = 0; cc < 4; ++cc) {
                    const float* p = ib + (size_t)((cblk * 4 + cc) * H_ + h - 1 + di) * W_ + dj;
                    tp[cc][di * 3 + dj] = o ? *p : 0.f;
                }
            }
        #pragma unroll
        for (int cc = 0; cc < 4; ++cc)
            #pragma unroll
            for (int pl = 0; pl < 2; ++pl) {
                f32x4 acc = w[pl][0] * tp[cc][0];
                #pragma unroll
                for (int k = 1; k < 9; ++k)
                    acc += w[pl][k] * tp[cc][k];
                *(f32x4*)(outb + ((size_t)(cblk * 4 + cc) * HO + pl) * WO) = acc;
            }
    }
}

extern "C" void kernel_launch(void* const* d_in, const int* in_sizes, int n_in,
                              void* d_out, int out_size, void* d_ws, size_t ws_size,
                              hipStream_t stream) {
    const float* inp  = (const float*)d_in[0];
    const float* mask = (const float*)d_in[1];
    float* out = (float*)d_out;
    const int blocks = N_ * H_ * 4;   // 8*48*4 = 1536
    raft_up_kernel<<<blocks, 256, 0, stream>>>(inp, mask, out);
}